// Round 24
// baseline (120.265 us; speedup 1.0000x reference)
//
#include <hip/hip_runtime.h>
#include <hip/hip_bf16.h>

typedef unsigned short u16;
typedef unsigned int u32;
typedef __attribute__((ext_vector_type(8))) short short8;
typedef __attribute__((ext_vector_type(4))) float f32x4;
typedef __attribute__((ext_vector_type(16))) float f32x16;
typedef __attribute__((ext_vector_type(2))) u32 u32x2;

typedef __attribute__((address_space(1))) void as1_void;
typedef __attribute__((address_space(3))) void as3_void;

// ---------- helpers ----------
__device__ __forceinline__ u16 f2b(float x) {
    union { float f; u32 u; } c; c.f = x;
    u32 r = c.u + 0x7fffu + ((c.u >> 16) & 1u);   // RNE, finite inputs
    return (u16)(r >> 16);
}
__device__ __forceinline__ float b2f(u16 x) {
    union { u32 u; float f; } c; c.u = ((u32)x) << 16;
    return c.f;
}
__device__ __forceinline__ u32 cvtpk(float lo, float hi) {   // S0 -> low16
    u32 r;
    asm("v_cvt_pk_bf16_f32 %0, %1, %2" : "=v"(r) : "v"(lo), "v"(hi));
    return r;
}
// async global->LDS, 16B per lane; LDS dest = wave-uniform base + lane*16
__device__ __forceinline__ void gload16(const u16* g, u16* l) {
    __builtin_amdgcn_global_load_lds((as1_void*)(u16*)g, (as3_void*)l, 16, 0, 0);
}
__device__ __forceinline__ void barrier_raw() {
    asm volatile("" ::: "memory");
    __builtin_amdgcn_s_barrier();
    asm volatile("" ::: "memory");
}

// ---------- fused prep: x fp32->bf16 convert + both weight transposes ----------
__device__ __forceinline__ void tbody(const float* __restrict__ in, u16* __restrict__ out,
                                      int R, int C, int r0, int c0, int t,
                                      u16 (&tile)[64][72]) {
    {
        const int rr = t >> 2;
        const int cq = (t & 3) * 16;
        const float* src = in + (size_t)(r0 + rr) * C + c0 + cq;
        #pragma unroll
        for (int j = 0; j < 4; j++) {
            float4 v = *(const float4*)(src + j * 4);
            tile[cq + j*4 + 0][rr] = f2b(v.x);
            tile[cq + j*4 + 1][rr] = f2b(v.y);
            tile[cq + j*4 + 2][rr] = f2b(v.z);
            tile[cq + j*4 + 3][rr] = f2b(v.w);
        }
    }
    __syncthreads();
    {
        const int cc = t >> 2;
        const int rq = (t & 3) * 16;
        u16* dst = out + (size_t)(c0 + cc) * R + r0 + rq;
        *(short8*)(dst)     = *(const short8*)&tile[cc][rq];
        *(short8*)(dst + 8) = *(const short8*)&tile[cc][rq + 8];
    }
}

__global__ __launch_bounds__(256) void prep_fused(const float* __restrict__ x,
                                                  const float* __restrict__ w_qkv,
                                                  const float* __restrict__ w_out,
                                                  u16* __restrict__ xb,
                                                  u16* __restrict__ wqkvT,
                                                  u16* __restrict__ woutT) {
    __shared__ u16 tile[64][72];
    const int b = blockIdx.x, t = threadIdx.x;
    if (b < 2048) {                       // x convert: 2048 blocks x 256 thr x 8 elems
        const int i = b * 256 + t;
        const float4* p = (const float4*)(x + (size_t)i * 8);
        float4 a = p[0], c = p[1];
        short8 v;
        v[0]=(short)f2b(a.x); v[1]=(short)f2b(a.y); v[2]=(short)f2b(a.z); v[3]=(short)f2b(a.w);
        v[4]=(short)f2b(c.x); v[5]=(short)f2b(c.y); v[6]=(short)f2b(c.z); v[7]=(short)f2b(c.w);
        *(short8*)(xb + (size_t)i * 8) = v;
    } else if (b < 2816) {                // w_qkv^T: 768 blocks == old dim3(48,16)
        const int bb = b - 2048;
        tbody(w_qkv, wqkvT, 1024, 3072, (bb / 48) * 64, (bb % 48) * 64, t, tile);
    } else {                              // w_out^T: 256 blocks == old dim3(16,16)
        const int bb = b - 2816;
        tbody(w_out, woutT, 1024, 1024, (bb >> 4) * 64, (bb & 15) * 64, t, tile);
    }
}

// ---------- bf16 GEMM (QKV): counted-vmcnt double-buffered global_load_lds ----
// (byte-identical to round-23 passing version)
__global__ __launch_bounds__(256) void gemm128(const u16* __restrict__ A,
                                               const u16* __restrict__ Bt,
                                               u16* __restrict__ Cp,
                                               u16* __restrict__ vt,
                                               int M, int Nn, int K) {
    __shared__ __align__(16) u16 a_lds[2][128 * 32];
    __shared__ __align__(16) u16 b_lds[2][128 * 32];
    const int tid = threadIdx.x;
    const int w = tid >> 6, l = tid & 63;
    const int l16 = l & 15, lg = l >> 4;
    const int nbx = gridDim.x;
    const int flat = blockIdx.x + nbx * blockIdx.y;
    const int cpx = (nbx * gridDim.y) >> 3;
    const int logical = (flat & 7) * cpx + (flat >> 3);
    const int m0 = (logical / nbx) * 128, n0 = (logical % nbx) * 128;
    const int wm = w >> 1, wn = w & 1;
    const int lr = l >> 2;               // lane row-in-call 0..15
    const int scol = (((l & 3) ^ ((lr >> 1) & 3)) * 8);   // u16 col, pre-swizzled
    const int rsl = (lg ^ ((l16 >> 1) & 3)) * 8;          // read-side swizzled slot

    f32x4 acc[4][4];
    #pragma unroll
    for (int i = 0; i < 4; i++)
        #pragma unroll
        for (int j = 0; j < 4; j++) { f32x4 z = {0.f,0.f,0.f,0.f}; acc[i][j] = z; }

    const u16* Ap = A  + (size_t)m0 * K;
    const u16* Bp = Bt + (size_t)n0 * K;

#define STAGE(BUF, KOF)                                                              \
    _Pragma("unroll")                                                                \
    for (int j = 0; j < 2; j++) {                                                    \
        const int r = w * 32 + j * 16;                                               \
        gload16(Ap + (size_t)(r + lr) * K + (KOF) + scol, &a_lds[(BUF)][r * 32]);    \
        gload16(Bp + (size_t)(r + lr) * K + (KOF) + scol, &b_lds[(BUF)][r * 32]);    \
    }

    const int nk = K >> 5;
    STAGE(0, 0)
    int cur = 0;
    for (int kt = 0; kt < nk; kt++) {
        if (kt + 1 < nk) {               // prefetch next tile; 4 loads stay in flight
            STAGE(cur ^ 1, (kt + 1) << 5)
            __builtin_amdgcn_sched_barrier(0);   // pin loads above the wait
            asm volatile("s_waitcnt vmcnt(4)" ::: "memory");
            __builtin_amdgcn_sched_barrier(0);
        } else {
            __builtin_amdgcn_sched_barrier(0);
            asm volatile("s_waitcnt vmcnt(0)" ::: "memory");
            __builtin_amdgcn_sched_barrier(0);
        }
        barrier_raw();                   // everyone's current tile landed
        short8 af[4], bf8[4];
        #pragma unroll
        for (int mb = 0; mb < 4; mb++)
            af[mb] = *(const short8*)&a_lds[cur][(wm * 64 + mb * 16 + l16) * 32 + rsl];
        #pragma unroll
        for (int nb = 0; nb < 4; nb++)
            bf8[nb] = *(const short8*)&b_lds[cur][(wn * 64 + nb * 16 + l16) * 32 + rsl];
        #pragma unroll
        for (int mb = 0; mb < 4; mb++)
            #pragma unroll
            for (int nb = 0; nb < 4; nb++)
                acc[mb][nb] = __builtin_amdgcn_mfma_f32_16x16x32_bf16(af[mb], bf8[nb], acc[mb][nb], 0, 0, 0);
        barrier_raw();                   // reads done before next overwrite
        cur ^= 1;
    }
#undef STAGE

    #pragma unroll
    for (int mb = 0; mb < 4; mb++) {
        #pragma unroll
        for (int nb = 0; nb < 4; nb++) {
            const int col = n0 + wn * 64 + nb * 16 + l16;
            const int row0 = m0 + wm * 64 + mb * 16 + lg * 4;
            if (col < 2048) {            // Q,K: row-major
                #pragma unroll
                for (int r = 0; r < 4; r++)
                    Cp[(size_t)(row0 + r) * Nn + col] = f2b(acc[mb][nb][r]);
            } else {                     // V: transposed into vt[b,h,d,n], 8B packed
                const int hd = col - 2048;
                const int hh = hd >> 6, d = hd & 63;
                const int bi = row0 >> 11, n = row0 & 2047;
                u32x2 pr;
                pr.x = cvtpk(acc[mb][nb][0], acc[mb][nb][1]);
                pr.y = cvtpk(acc[mb][nb][2], acc[mb][nb][3]);
                *(u32x2*)(vt + ((size_t)((bi * 16 + hh) * 64 + d)) * 2048 + n) = pr;
            }
        }
    }
}

// ---------- bf16 GEMM (out-proj): 64x128 tile, fp32+bias epilogue ----------
// (byte-identical to round-21/23 passing version)
__global__ __launch_bounds__(256) void gemm64n(const u16* __restrict__ A,
                                               const u16* __restrict__ Bt,
                                               float* __restrict__ Cp,
                                               const float* __restrict__ bias,
                                               int M, int Nn, int K) {
    __shared__ __align__(16) u16 a_lds[2][64 * 32];
    __shared__ __align__(16) u16 b_lds[2][128 * 32];
    const int tid = threadIdx.x;
    const int w = tid >> 6, l = tid & 63;
    const int l16 = l & 15, lg = l >> 4;
    const int nbx = gridDim.x;
    const int flat = blockIdx.x + nbx * blockIdx.y;
    const int cpx = (nbx * gridDim.y) >> 3;
    const int logical = (flat & 7) * cpx + (flat >> 3);
    const int m0 = (logical / nbx) * 64, n0 = (logical % nbx) * 128;
    const int wm = w >> 1, wn = w & 1;
    const int lr = l >> 2;               // lane row-in-call 0..15
    const int scol = (((l & 3) ^ ((lr >> 1) & 3)) * 8);   // u16 col, pre-swizzled
    const int rsl = (lg ^ ((l16 >> 1) & 3)) * 8;          // read-side swizzled slot

    f32x4 acc[2][4];
    #pragma unroll
    for (int i = 0; i < 2; i++)
        #pragma unroll
        for (int j = 0; j < 4; j++) { f32x4 z = {0.f,0.f,0.f,0.f}; acc[i][j] = z; }

    const u16* Ap = A  + (size_t)m0 * K;
    const u16* Bp = Bt + (size_t)n0 * K;

#define STAGE64(BUF, KOF)                                                            \
    gload16(Ap + (size_t)(w * 16 + lr) * K + (KOF) + scol, &a_lds[(BUF)][w * 16 * 32]); \
    _Pragma("unroll")                                                                \
    for (int j = 0; j < 2; j++) {                                                    \
        const int r = w * 32 + j * 16;                                               \
        gload16(Bp + (size_t)(r + lr) * K + (KOF) + scol, &b_lds[(BUF)][r * 32]);    \
    }

    const int nk = K >> 5;
    STAGE64(0, 0)
    int cur = 0;
    for (int kt = 0; kt < nk; kt++) {
        if (kt + 1 < nk) {               // prefetch next tile; 3 loads stay in flight
            STAGE64(cur ^ 1, (kt + 1) << 5)
            __builtin_amdgcn_sched_barrier(0);
            asm volatile("s_waitcnt vmcnt(3)" ::: "memory");
            __builtin_amdgcn_sched_barrier(0);
        } else {
            __builtin_amdgcn_sched_barrier(0);
            asm volatile("s_waitcnt vmcnt(0)" ::: "memory");
            __builtin_amdgcn_sched_barrier(0);
        }
        barrier_raw();                   // everyone's current tile landed
        short8 af[2], bf8[4];
        #pragma unroll
        for (int mb = 0; mb < 2; mb++)
            af[mb] = *(const short8*)&a_lds[cur][(wm * 32 + mb * 16 + l16) * 32 + rsl];
        #pragma unroll
        for (int nb = 0; nb < 4; nb++)
            bf8[nb] = *(const short8*)&b_lds[cur][(wn * 64 + nb * 16 + l16) * 32 + rsl];
        #pragma unroll
        for (int mb = 0; mb < 2; mb++)
            #pragma unroll
            for (int nb = 0; nb < 4; nb++)
                acc[mb][nb] = __builtin_amdgcn_mfma_f32_16x16x32_bf16(af[mb], bf8[nb], acc[mb][nb], 0, 0, 0);
        barrier_raw();                   // reads done before next overwrite
        cur ^= 1;
    }
#undef STAGE64

    #pragma unroll
    for (int mb = 0; mb < 2; mb++) {
        #pragma unroll
        for (int nb = 0; nb < 4; nb++) {
            const int col = n0 + wn * 64 + nb * 16 + l16;
            const int row0 = m0 + wm * 32 + mb * 16 + lg * 4;
            #pragma unroll
            for (int r = 0; r < 4; r++)
                Cp[(size_t)(row0 + r) * Nn + col] = acc[mb][nb][r] + bias[col];
        }
    }
}

// ---------- flash attention: 4 waves x 32 Q-rows, swapped QK^T / PV ----------
// Round-23 structure (4-buf rotation, 16 barriers, reg-staged K/V, serial
// reductions). ONLY change: T5 s_setprio(1)/(0) around both MFMA clusters —
// arbitrates against the co-resident block's staging/softmax waves (m191).
__global__ __launch_bounds__(256, 2) void attn_kernel(const u16* __restrict__ qkv,
                                                      const u16* __restrict__ vt,
                                                      u16* __restrict__ out) {
    __shared__ __align__(16) u16 k_lds[16384];  // 4 bufs x [64 kv][64 d] swizzled
    __shared__ __align__(16) u16 v_lds[16384];  // 4 bufs x [64 d][64 kv] swizzled
    const int tid = threadIdx.x;
    const int w = tid >> 6, l = tid & 63;
    const int l31 = l & 31, hi = l >> 5;
    // XCD swizzle: 512 blocks, cpx=64 -> each XCD owns 4 full (b,h) KV groups
    const int flat = blockIdx.x + (blockIdx.y << 4) + (blockIdx.z << 8);
    const int logical = (flat & 7) * 64 + (flat >> 3);
    const int xq = logical & 15, h = (logical >> 4) & 15, bb = logical >> 8;
    const int q0 = xq * 128 + w * 32;
    const int swzl = (l31 & 7) << 3;            // u16-unit XOR for 16B-slot swizzle

    // Q fragments, pre-scaled by 0.125 (exact exponent shift in bf16)
    const u16* qp = qkv + (size_t)(bb * 2048 + q0 + l31) * 3072 + h * 64 + hi * 8;
    short8 qf[4];
    #pragma unroll
    for (int c4 = 0; c4 < 4; c4++) {
        short8 v = *(const short8*)(qp + c4 * 16);
        #pragma unroll
        for (int e = 0; e < 8; e++) v[e] = (short)f2b(b2f((u16)v[e]) * 0.125f);
        qf[c4] = v;
    }

    f32x16 o[2];
    #pragma unroll
    for (int d0 = 0; d0 < 2; d0++)
        #pragma unroll
        for (int e = 0; e < 16; e++) o[d0][e] = 0.f;
    float mrow = -1e30f, lsum = 0.f;

    // staging: 256 threads, 2 slots/thread per matrix; row = tid>>2, slots {sc, sc+4}
    const int srow = tid >> 2, sc = tid & 3;
    const int kd0 = srow * 64 + ((sc ^ (srow & 7)) * 8);
    const int kd1 = srow * 64 + (((sc + 4) ^ (srow & 7)) * 8);
    const u16* ksrc = qkv + (size_t)(bb * 2048 + srow) * 3072 + 1024 + h * 64 + sc * 8;
    const u16* vsrc = vt + (size_t)((bb * 16 + h) * 64 + srow) * 2048 + sc * 8;

    short8 kr0, kr1, vr0, vr1;
    // prologue: fill bufs 0 (tile 0) and 4096 (tile 1)
    kr0 = *(const short8*)ksrc; kr1 = *(const short8*)(ksrc + 32);
    vr0 = *(const short8*)vsrc; vr1 = *(const short8*)(vsrc + 32);
    ksrc += 64 * 3072; vsrc += 64;
    *(short8*)&k_lds[kd0] = kr0; *(short8*)&k_lds[kd1] = kr1;
    *(short8*)&v_lds[kd0] = vr0; *(short8*)&v_lds[kd1] = vr1;
    kr0 = *(const short8*)ksrc; kr1 = *(const short8*)(ksrc + 32);
    vr0 = *(const short8*)vsrc; vr1 = *(const short8*)(vsrc + 32);
    ksrc += 64 * 3072; vsrc += 64;
    *(short8*)&k_lds[4096 + kd0] = kr0; *(short8*)&k_lds[4096 + kd1] = kr1;
    *(short8*)&v_lds[4096 + kd0] = vr0; *(short8*)&v_lds[4096 + kd1] = vr1;
    __syncthreads();

// DO_TILE: load regs for tile L (ksrc cursor), compute CUR, write L into NXT.
// No trailing barrier — barriers are placed per half-period in the loop.
#define DO_TILE(CUR, NXT)                                                               \
  {                                                                                     \
    kr0 = *(const short8*)ksrc; kr1 = *(const short8*)(ksrc + 32);                      \
    vr0 = *(const short8*)vsrc; vr1 = *(const short8*)(vsrc + 32);                      \
    ksrc += 64 * 3072; vsrc += 64;                                                      \
    f32x16 st[2];                                                                       \
    _Pragma("unroll") for (int tt = 0; tt < 2; tt++)                                    \
      _Pragma("unroll") for (int e = 0; e < 16; e++) st[tt][e] = 0.f;                   \
    __builtin_amdgcn_s_setprio(1);                                                      \
    _Pragma("unroll")                                                                   \
    for (int c4 = 0; c4 < 4; c4++) {                                                    \
      short8 kf0 = *(const short8*)&k_lds[(CUR) + (l31)*64      + ((c4*16 + hi*8) ^ swzl)]; \
      short8 kf1 = *(const short8*)&k_lds[(CUR) + (32 + l31)*64 + ((c4*16 + hi*8) ^ swzl)]; \
      st[0] = __builtin_amdgcn_mfma_f32_32x32x16_bf16(kf0, qf[c4], st[0], 0, 0, 0);     \
      st[1] = __builtin_amdgcn_mfma_f32_32x32x16_bf16(kf1, qf[c4], st[1], 0, 0, 0);     \
    }                                                                                   \
    __builtin_amdgcn_s_setprio(0);                                                      \
    float pmax = st[0][0];                                                              \
    _Pragma("unroll") for (int e = 1; e < 16; e++) pmax = fmaxf(pmax, st[0][e]);        \
    _Pragma("unroll") for (int e = 0; e < 16; e++) pmax = fmaxf(pmax, st[1][e]);        \
    const float rowm = fmaxf(pmax, __shfl_xor(pmax, 32));                               \
    if (__any(rowm > mrow + 5.5451774f)) {      /* T13 defer-max, THR = 8*ln2 */        \
      const float mnew  = fmaxf(mrow, rowm);                                            \
      const float alpha = __expf(mrow - mnew);                                          \
      lsum *= alpha;                                                                    \
      _Pragma("unroll") for (int d0 = 0; d0 < 2; d0++)                                  \
        _Pragma("unroll") for (int e = 0; e < 16; e++) o[d0][e] *= alpha;               \
      mrow = mnew;                                                                      \
    }                                                                                   \
    _Pragma("unroll") for (int tt = 0; tt < 2; tt++)                                    \
      _Pragma("unroll") for (int e = 0; e < 16; e++) st[tt][e] = __expf(st[tt][e] - mrow); \
    float psum = 0.f;                                                                   \
    _Pragma("unroll") for (int tt = 0; tt < 2; tt++)                                    \
      _Pragma("unroll") for (int e = 0; e < 16; e++) psum += st[tt][e];                 \
    lsum += psum + __shfl_xor(psum, 32);                                                \
    short8 pb[4];                                                                       \
    _Pragma("unroll")                                                                   \
    for (int tt = 0; tt < 2; tt++) {                                                    \
      _Pragma("unroll")                                                                 \
      for (int g = 0; g < 2; g++) {                                                     \
        /* own words: w0 kv=16g+{0,1}+4hi, w1 kv=16g+{2,3}+4hi,                         \
                      w2 kv=16g+8+{0,1}+4hi, w3 kv=16g+8+{2,3}+4hi                      \
           B-frag element (hi,i) needs kv = 16g + 8*hi + i                           */ \
        u32 w0 = cvtpk(st[tt][8*g + 0], st[tt][8*g + 1]);                               \
        u32 w1 = cvtpk(st[tt][8*g + 2], st[tt][8*g + 3]);                               \
        u32 w2 = cvtpk(st[tt][8*g + 4], st[tt][8*g + 5]);                               \
        u32 w3 = cvtpk(st[tt][8*g + 6], st[tt][8*g + 7]);                               \
        u32 w0x = (u32)__shfl_xor((int)w0, 32);                                         \
        u32 w1x = (u32)__shfl_xor((int)w1, 32);                                         \
        u32 w2x = (u32)__shfl_xor((int)w2, 32);                                         \
        u32 w3x = (u32)__shfl_xor((int)w3, 32);                                         \
        union { u32 wd[4]; short8 s8; } uu;                                             \
        uu.wd[0] = hi ? w2x : w0;                                                       \
        uu.wd[1] = hi ? w3x : w1;                                                       \
        uu.wd[2] = hi ? w2  : w0x;                                                      \
        uu.wd[3] = hi ? w3  : w1x;                                                      \
        pb[2*tt + g] = uu.s8;                                                           \
      }                                                                                 \
    }                                                                                   \
    __builtin_amdgcn_s_setprio(1);                                                      \
    _Pragma("unroll")                                                                   \
    for (int ks = 0; ks < 4; ks++) {                                                    \
      short8 vf0 = *(const short8*)&v_lds[(CUR) + (l31)*64      + ((ks*16 + hi*8) ^ swzl)]; \
      short8 vf1 = *(const short8*)&v_lds[(CUR) + (32 + l31)*64 + ((ks*16 + hi*8) ^ swzl)]; \
      o[0] = __builtin_amdgcn_mfma_f32_32x32x16_bf16(vf0, pb[ks], o[0], 0, 0, 0);       \
      o[1] = __builtin_amdgcn_mfma_f32_32x32x16_bf16(vf1, pb[ks], o[1], 0, 0, 0);       \
    }                                                                                   \
    __builtin_amdgcn_s_setprio(0);                                                      \
    *(short8*)&k_lds[(NXT) + kd0] = kr0; *(short8*)&k_lds[(NXT) + kd1] = kr1;           \
    *(short8*)&v_lds[(NXT) + kd0] = vr0; *(short8*)&v_lds[(NXT) + kd1] = vr1;           \
  }

    for (int it = 0; it < 8; it++) {
        DO_TILE(0, 8192)                 // compute t,   write t+2 -> buf2
        DO_TILE(4096, 12288)             // compute t+1, write t+3 -> buf3
        __syncthreads();                 // buf2/3 ready; buf0/1 reads done
        DO_TILE(8192, 0)                 // compute t+2, write t+4 -> buf0
        DO_TILE(12288, 4096)             // compute t+3, write t+5 -> buf1
        __syncthreads();                 // buf0/1 ready; buf2/3 reads done
    }
#undef DO_TILE

    // epilogue: O^T layout col=q (lane-local), row d = d0*32 + 8s + 4hi + j
    const float invl = 1.0f / lsum;
    u16* op = out + (size_t)(bb * 2048 + q0 + l31) * 1024 + h * 64;
    #pragma unroll
    for (int d0 = 0; d0 < 2; d0++) {
        #pragma unroll
        for (int s = 0; s < 4; s++) {
            u32x2 pr;
            pr.x = cvtpk(o[d0][4*s + 0] * invl, o[d0][4*s + 1] * invl);
            pr.y = cvtpk(o[d0][4*s + 2] * invl, o[d0][4*s + 3] * invl);
            *(u32x2*)(op + d0 * 32 + s * 8 + hi * 4) = pr;
        }
    }
}

// ---------- launcher ----------
extern "C" void kernel_launch(void* const* d_in, const int* in_sizes, int n_in,
                              void* d_out, int out_size, void* d_ws, size_t ws_size,
                              hipStream_t stream) {
    const float* x     = (const float*)d_in[0];   // [2,2048,1024]
    const float* w_qkv = (const float*)d_in[1];   // [1024,3072]
    const float* w_out = (const float*)d_in[2];   // [1024,1024]
    const float* b_out = (const float*)d_in[3];   // [1024]

    char* ws = (char*)d_ws;
    u16* xb    = (u16*)(ws);                          //  8 MB  x bf16 [4096,1024]
    u16* wqkvT = (u16*)(ws + (size_t)( 8u << 20));    //  6 MB  w_qkv^T bf16 [3072,1024]
    u16* woutT = (u16*)(ws + (size_t)(14u << 20));    //  2 MB  w_out^T bf16 [1024,1024]
    u16* qkvb  = (u16*)(ws + (size_t)(16u << 20));    // 24 MB  q,k bf16 [4096,3072]
    u16* vtb   = (u16*)(ws + (size_t)(40u << 20));    //  8 MB  v^T bf16 [b,h,64,2048]
    u16* aout  = (u16*)(ws + (size_t)(48u << 20));    //  8 MB  attn out bf16 [4096,1024]

    prep_fused<<<3072, 256, 0, stream>>>(x, w_qkv, w_out, xb, wqkvT, woutT);

    gemm128<<<dim3(24, 32), 256, 0, stream>>>(xb, wqkvT, qkvb, vtb, 4096, 3072, 1024);
    attn_kernel<<<dim3(16, 16, 2), 256, 0, stream>>>(qkvb, vtb, aout);

    gemm64n<<<dim3(8, 64), 256, 0, stream>>>(aout, woutT, (float*)d_out, b_out,
                                             4096, 1024, 1024);
}

// Round 25
// 118.189 us; speedup vs baseline: 1.0176x; 1.0176x over previous
//
#include <hip/hip_runtime.h>
#include <hip/hip_bf16.h>

typedef unsigned short u16;
typedef unsigned int u32;
typedef __attribute__((ext_vector_type(8))) short short8;
typedef __attribute__((ext_vector_type(4))) float f32x4;
typedef __attribute__((ext_vector_type(16))) float f32x16;
typedef __attribute__((ext_vector_type(2))) u32 u32x2;

typedef __attribute__((address_space(1))) void as1_void;
typedef __attribute__((address_space(3))) void as3_void;

// ---------- helpers ----------
__device__ __forceinline__ u16 f2b(float x) {
    union { float f; u32 u; } c; c.f = x;
    u32 r = c.u + 0x7fffu + ((c.u >> 16) & 1u);   // RNE, finite inputs
    return (u16)(r >> 16);
}
__device__ __forceinline__ float b2f(u16 x) {
    union { u32 u; float f; } c; c.u = ((u32)x) << 16;
    return c.f;
}
__device__ __forceinline__ u32 cvtpk(float lo, float hi) {   // S0 -> low16
    u32 r;
    asm("v_cvt_pk_bf16_f32 %0, %1, %2" : "=v"(r) : "v"(lo), "v"(hi));
    return r;
}
// async global->LDS, 16B per lane; LDS dest = wave-uniform base + lane*16
__device__ __forceinline__ void gload16(const u16* g, u16* l) {
    __builtin_amdgcn_global_load_lds((as1_void*)(u16*)g, (as3_void*)l, 16, 0, 0);
}
__device__ __forceinline__ void barrier_raw() {
    asm volatile("" ::: "memory");
    __builtin_amdgcn_s_barrier();
    asm volatile("" ::: "memory");
}

// ---------- fused prep: x fp32->bf16 convert + both weight transposes ----------
__device__ __forceinline__ void tbody(const float* __restrict__ in, u16* __restrict__ out,
                                      int R, int C, int r0, int c0, int t,
                                      u16 (&tile)[64][72]) {
    {
        const int rr = t >> 2;
        const int cq = (t & 3) * 16;
        const float* src = in + (size_t)(r0 + rr) * C + c0 + cq;
        #pragma unroll
        for (int j = 0; j < 4; j++) {
            float4 v = *(const float4*)(src + j * 4);
            tile[cq + j*4 + 0][rr] = f2b(v.x);
            tile[cq + j*4 + 1][rr] = f2b(v.y);
            tile[cq + j*4 + 2][rr] = f2b(v.z);
            tile[cq + j*4 + 3][rr] = f2b(v.w);
        }
    }
    __syncthreads();
    {
        const int cc = t >> 2;
        const int rq = (t & 3) * 16;
        u16* dst = out + (size_t)(c0 + cc) * R + r0 + rq;
        *(short8*)(dst)     = *(const short8*)&tile[cc][rq];
        *(short8*)(dst + 8) = *(const short8*)&tile[cc][rq + 8];
    }
}

__global__ __launch_bounds__(256) void prep_fused(const float* __restrict__ x,
                                                  const float* __restrict__ w_qkv,
                                                  const float* __restrict__ w_out,
                                                  u16* __restrict__ xb,
                                                  u16* __restrict__ wqkvT,
                                                  u16* __restrict__ woutT) {
    __shared__ u16 tile[64][72];
    const int b = blockIdx.x, t = threadIdx.x;
    if (b < 2048) {                       // x convert: 2048 blocks x 256 thr x 8 elems
        const int i = b * 256 + t;
        const float4* p = (const float4*)(x + (size_t)i * 8);
        float4 a = p[0], c = p[1];
        short8 v;
        v[0]=(short)f2b(a.x); v[1]=(short)f2b(a.y); v[2]=(short)f2b(a.z); v[3]=(short)f2b(a.w);
        v[4]=(short)f2b(c.x); v[5]=(short)f2b(c.y); v[6]=(short)f2b(c.z); v[7]=(short)f2b(c.w);
        *(short8*)(xb + (size_t)i * 8) = v;
    } else if (b < 2816) {                // w_qkv^T: 768 blocks == old dim3(48,16)
        const int bb = b - 2048;
        tbody(w_qkv, wqkvT, 1024, 3072, (bb / 48) * 64, (bb % 48) * 64, t, tile);
    } else {                              // w_out^T: 256 blocks == old dim3(16,16)
        const int bb = b - 2816;
        tbody(w_out, woutT, 1024, 1024, (bb >> 4) * 64, (bb & 15) * 64, t, tile);
    }
}

// ---------- bf16 GEMM (QKV): counted-vmcnt double-buffered global_load_lds ----
// 128x128 tile, BK=32, 4 waves (2x2), 16x16x32 MFMA. XCD-aware block swizzle.
// LDS bank swizzle: slot ^= (row>>1)&3 on BOTH the pre-swizzled global source
// and the ds_read address (involution).
// u16 out; V columns (>=2048) stored transposed into vt[b,h,d,n].
__global__ __launch_bounds__(256) void gemm128(const u16* __restrict__ A,
                                               const u16* __restrict__ Bt,
                                               u16* __restrict__ Cp,
                                               u16* __restrict__ vt,
                                               int M, int Nn, int K) {
    __shared__ __align__(16) u16 a_lds[2][128 * 32];
    __shared__ __align__(16) u16 b_lds[2][128 * 32];
    const int tid = threadIdx.x;
    const int w = tid >> 6, l = tid & 63;
    const int l16 = l & 15, lg = l >> 4;
    const int nbx = gridDim.x;
    const int flat = blockIdx.x + nbx * blockIdx.y;
    const int cpx = (nbx * gridDim.y) >> 3;
    const int logical = (flat & 7) * cpx + (flat >> 3);
    const int m0 = (logical / nbx) * 128, n0 = (logical % nbx) * 128;
    const int wm = w >> 1, wn = w & 1;
    const int lr = l >> 2;               // lane row-in-call 0..15
    const int scol = (((l & 3) ^ ((lr >> 1) & 3)) * 8);   // u16 col, pre-swizzled
    const int rsl = (lg ^ ((l16 >> 1) & 3)) * 8;          // read-side swizzled slot

    f32x4 acc[4][4];
    #pragma unroll
    for (int i = 0; i < 4; i++)
        #pragma unroll
        for (int j = 0; j < 4; j++) { f32x4 z = {0.f,0.f,0.f,0.f}; acc[i][j] = z; }

    const u16* Ap = A  + (size_t)m0 * K;
    const u16* Bp = Bt + (size_t)n0 * K;

#define STAGE(BUF, KOF)                                                              \
    _Pragma("unroll")                                                                \
    for (int j = 0; j < 2; j++) {                                                    \
        const int r = w * 32 + j * 16;                                               \
        gload16(Ap + (size_t)(r + lr) * K + (KOF) + scol, &a_lds[(BUF)][r * 32]);    \
        gload16(Bp + (size_t)(r + lr) * K + (KOF) + scol, &b_lds[(BUF)][r * 32]);    \
    }

    const int nk = K >> 5;
    STAGE(0, 0)
    int cur = 0;
    for (int kt = 0; kt < nk; kt++) {
        if (kt + 1 < nk) {               // prefetch next tile; 4 loads stay in flight
            STAGE(cur ^ 1, (kt + 1) << 5)
            __builtin_amdgcn_sched_barrier(0);   // pin loads above the wait
            asm volatile("s_waitcnt vmcnt(4)" ::: "memory");
            __builtin_amdgcn_sched_barrier(0);
        } else {
            __builtin_amdgcn_sched_barrier(0);
            asm volatile("s_waitcnt vmcnt(0)" ::: "memory");
            __builtin_amdgcn_sched_barrier(0);
        }
        barrier_raw();                   // everyone's current tile landed
        short8 af[4], bf8[4];
        #pragma unroll
        for (int mb = 0; mb < 4; mb++)
            af[mb] = *(const short8*)&a_lds[cur][(wm * 64 + mb * 16 + l16) * 32 + rsl];
        #pragma unroll
        for (int nb = 0; nb < 4; nb++)
            bf8[nb] = *(const short8*)&b_lds[cur][(wn * 64 + nb * 16 + l16) * 32 + rsl];
        #pragma unroll
        for (int mb = 0; mb < 4; mb++)
            #pragma unroll
            for (int nb = 0; nb < 4; nb++)
                acc[mb][nb] = __builtin_amdgcn_mfma_f32_16x16x32_bf16(af[mb], bf8[nb], acc[mb][nb], 0, 0, 0);
        barrier_raw();                   // reads done before next overwrite
        cur ^= 1;
    }
#undef STAGE

    #pragma unroll
    for (int mb = 0; mb < 4; mb++) {
        #pragma unroll
        for (int nb = 0; nb < 4; nb++) {
            const int col = n0 + wn * 64 + nb * 16 + l16;
            const int row0 = m0 + wm * 64 + mb * 16 + lg * 4;
            if (col < 2048) {            // Q,K: row-major
                #pragma unroll
                for (int r = 0; r < 4; r++)
                    Cp[(size_t)(row0 + r) * Nn + col] = f2b(acc[mb][nb][r]);
            } else {                     // V: transposed into vt[b,h,d,n], 8B packed
                const int hd = col - 2048;
                const int hh = hd >> 6, d = hd & 63;
                const int bi = row0 >> 11, n = row0 & 2047;
                u32x2 pr;
                pr.x = cvtpk(acc[mb][nb][0], acc[mb][nb][1]);
                pr.y = cvtpk(acc[mb][nb][2], acc[mb][nb][3]);
                *(u32x2*)(vt + ((size_t)((bi * 16 + hh) * 64 + d)) * 2048 + n) = pr;
            }
        }
    }
}

// ---------- bf16 GEMM (out-proj): 64x128 tile, fp32+bias epilogue ----------
// Same structure as gemm128 re-parameterized: 4 waves 2x2 over 64x128 (per-wave
// 32x64, acc[2][4]); A-tile 64 rows (1 gload16/wave), vmcnt(3) (3 loads/stage).
// Grid (8,64) = 512 blocks -> 2 blocks/CU so barrier stalls overlap.
__global__ __launch_bounds__(256) void gemm64n(const u16* __restrict__ A,
                                               const u16* __restrict__ Bt,
                                               float* __restrict__ Cp,
                                               const float* __restrict__ bias,
                                               int M, int Nn, int K) {
    __shared__ __align__(16) u16 a_lds[2][64 * 32];
    __shared__ __align__(16) u16 b_lds[2][128 * 32];
    const int tid = threadIdx.x;
    const int w = tid >> 6, l = tid & 63;
    const int l16 = l & 15, lg = l >> 4;
    const int nbx = gridDim.x;
    const int flat = blockIdx.x + nbx * blockIdx.y;
    const int cpx = (nbx * gridDim.y) >> 3;
    const int logical = (flat & 7) * cpx + (flat >> 3);
    const int m0 = (logical / nbx) * 64, n0 = (logical % nbx) * 128;
    const int wm = w >> 1, wn = w & 1;
    const int lr = l >> 2;               // lane row-in-call 0..15
    const int scol = (((l & 3) ^ ((lr >> 1) & 3)) * 8);   // u16 col, pre-swizzled
    const int rsl = (lg ^ ((l16 >> 1) & 3)) * 8;          // read-side swizzled slot

    f32x4 acc[2][4];
    #pragma unroll
    for (int i = 0; i < 2; i++)
        #pragma unroll
        for (int j = 0; j < 4; j++) { f32x4 z = {0.f,0.f,0.f,0.f}; acc[i][j] = z; }

    const u16* Ap = A  + (size_t)m0 * K;
    const u16* Bp = Bt + (size_t)n0 * K;

#define STAGE64(BUF, KOF)                                                            \
    gload16(Ap + (size_t)(w * 16 + lr) * K + (KOF) + scol, &a_lds[(BUF)][w * 16 * 32]); \
    _Pragma("unroll")                                                                \
    for (int j = 0; j < 2; j++) {                                                    \
        const int r = w * 32 + j * 16;                                               \
        gload16(Bp + (size_t)(r + lr) * K + (KOF) + scol, &b_lds[(BUF)][r * 32]);    \
    }

    const int nk = K >> 5;
    STAGE64(0, 0)
    int cur = 0;
    for (int kt = 0; kt < nk; kt++) {
        if (kt + 1 < nk) {               // prefetch next tile; 3 loads stay in flight
            STAGE64(cur ^ 1, (kt + 1) << 5)
            __builtin_amdgcn_sched_barrier(0);
            asm volatile("s_waitcnt vmcnt(3)" ::: "memory");
            __builtin_amdgcn_sched_barrier(0);
        } else {
            __builtin_amdgcn_sched_barrier(0);
            asm volatile("s_waitcnt vmcnt(0)" ::: "memory");
            __builtin_amdgcn_sched_barrier(0);
        }
        barrier_raw();                   // everyone's current tile landed
        short8 af[2], bf8[4];
        #pragma unroll
        for (int mb = 0; mb < 2; mb++)
            af[mb] = *(const short8*)&a_lds[cur][(wm * 32 + mb * 16 + l16) * 32 + rsl];
        #pragma unroll
        for (int nb = 0; nb < 4; nb++)
            bf8[nb] = *(const short8*)&b_lds[cur][(wn * 64 + nb * 16 + l16) * 32 + rsl];
        #pragma unroll
        for (int mb = 0; mb < 2; mb++)
            #pragma unroll
            for (int nb = 0; nb < 4; nb++)
                acc[mb][nb] = __builtin_amdgcn_mfma_f32_16x16x32_bf16(af[mb], bf8[nb], acc[mb][nb], 0, 0, 0);
        barrier_raw();                   // reads done before next overwrite
        cur ^= 1;
    }
#undef STAGE64

    #pragma unroll
    for (int mb = 0; mb < 2; mb++) {
        #pragma unroll
        for (int nb = 0; nb < 4; nb++) {
            const int col = n0 + wn * 64 + nb * 16 + l16;
            const int row0 = m0 + wm * 32 + mb * 16 + lg * 4;
            #pragma unroll
            for (int r = 0; r < 4; r++)
                Cp[(size_t)(row0 + r) * Nn + col] = acc[mb][nb][r] + bias[col];
        }
    }
}

// ---------- flash attention: 4 waves x 32 Q-rows, swapped QK^T / PV ----------
// Final: 4-buffer rotation, 2 KV-tiles per barrier period (16 barriers),
// serial row reductions, reg-staged K/V. (setprio tested R24: -2.7us attn,
// reverted — intra-block lockstep leaves nothing to arbitrate.)
__global__ __launch_bounds__(256, 2) void attn_kernel(const u16* __restrict__ qkv,
                                                      const u16* __restrict__ vt,
                                                      u16* __restrict__ out) {
    __shared__ __align__(16) u16 k_lds[16384];  // 4 bufs x [64 kv][64 d] swizzled
    __shared__ __align__(16) u16 v_lds[16384];  // 4 bufs x [64 d][64 kv] swizzled
    const int tid = threadIdx.x;
    const int w = tid >> 6, l = tid & 63;
    const int l31 = l & 31, hi = l >> 5;
    // XCD swizzle: 512 blocks, cpx=64 -> each XCD owns 4 full (b,h) KV groups
    const int flat = blockIdx.x + (blockIdx.y << 4) + (blockIdx.z << 8);
    const int logical = (flat & 7) * 64 + (flat >> 3);
    const int xq = logical & 15, h = (logical >> 4) & 15, bb = logical >> 8;
    const int q0 = xq * 128 + w * 32;
    const int swzl = (l31 & 7) << 3;            // u16-unit XOR for 16B-slot swizzle

    // Q fragments, pre-scaled by 0.125 (exact exponent shift in bf16)
    const u16* qp = qkv + (size_t)(bb * 2048 + q0 + l31) * 3072 + h * 64 + hi * 8;
    short8 qf[4];
    #pragma unroll
    for (int c4 = 0; c4 < 4; c4++) {
        short8 v = *(const short8*)(qp + c4 * 16);
        #pragma unroll
        for (int e = 0; e < 8; e++) v[e] = (short)f2b(b2f((u16)v[e]) * 0.125f);
        qf[c4] = v;
    }

    f32x16 o[2];
    #pragma unroll
    for (int d0 = 0; d0 < 2; d0++)
        #pragma unroll
        for (int e = 0; e < 16; e++) o[d0][e] = 0.f;
    float mrow = -1e30f, lsum = 0.f;

    // staging: 256 threads, 2 slots/thread per matrix; row = tid>>2, slots {sc, sc+4}
    const int srow = tid >> 2, sc = tid & 3;
    const int kd0 = srow * 64 + ((sc ^ (srow & 7)) * 8);
    const int kd1 = srow * 64 + (((sc + 4) ^ (srow & 7)) * 8);
    const u16* ksrc = qkv + (size_t)(bb * 2048 + srow) * 3072 + 1024 + h * 64 + sc * 8;
    const u16* vsrc = vt + (size_t)((bb * 16 + h) * 64 + srow) * 2048 + sc * 8;

    short8 kr0, kr1, vr0, vr1;
    // prologue: fill bufs 0 (tile 0) and 4096 (tile 1)
    kr0 = *(const short8*)ksrc; kr1 = *(const short8*)(ksrc + 32);
    vr0 = *(const short8*)vsrc; vr1 = *(const short8*)(vsrc + 32);
    ksrc += 64 * 3072; vsrc += 64;
    *(short8*)&k_lds[kd0] = kr0; *(short8*)&k_lds[kd1] = kr1;
    *(short8*)&v_lds[kd0] = vr0; *(short8*)&v_lds[kd1] = vr1;
    kr0 = *(const short8*)ksrc; kr1 = *(const short8*)(ksrc + 32);
    vr0 = *(const short8*)vsrc; vr1 = *(const short8*)(vsrc + 32);
    ksrc += 64 * 3072; vsrc += 64;
    *(short8*)&k_lds[4096 + kd0] = kr0; *(short8*)&k_lds[4096 + kd1] = kr1;
    *(short8*)&v_lds[4096 + kd0] = vr0; *(short8*)&v_lds[4096 + kd1] = vr1;
    __syncthreads();

// DO_TILE: load regs for tile L (ksrc cursor), compute CUR, write L into NXT.
// No trailing barrier — barriers are placed per half-period in the loop.
#define DO_TILE(CUR, NXT)                                                               \
  {                                                                                     \
    kr0 = *(const short8*)ksrc; kr1 = *(const short8*)(ksrc + 32);                      \
    vr0 = *(const short8*)vsrc; vr1 = *(const short8*)(vsrc + 32);                      \
    ksrc += 64 * 3072; vsrc += 64;                                                      \
    f32x16 st[2];                                                                       \
    _Pragma("unroll") for (int tt = 0; tt < 2; tt++)                                    \
      _Pragma("unroll") for (int e = 0; e < 16; e++) st[tt][e] = 0.f;                   \
    _Pragma("unroll")                                                                   \
    for (int c4 = 0; c4 < 4; c4++) {                                                    \
      short8 kf0 = *(const short8*)&k_lds[(CUR) + (l31)*64      + ((c4*16 + hi*8) ^ swzl)]; \
      short8 kf1 = *(const short8*)&k_lds[(CUR) + (32 + l31)*64 + ((c4*16 + hi*8) ^ swzl)]; \
      st[0] = __builtin_amdgcn_mfma_f32_32x32x16_bf16(kf0, qf[c4], st[0], 0, 0, 0);     \
      st[1] = __builtin_amdgcn_mfma_f32_32x32x16_bf16(kf1, qf[c4], st[1], 0, 0, 0);     \
    }                                                                                   \
    float pmax = st[0][0];                                                              \
    _Pragma("unroll") for (int e = 1; e < 16; e++) pmax = fmaxf(pmax, st[0][e]);        \
    _Pragma("unroll") for (int e = 0; e < 16; e++) pmax = fmaxf(pmax, st[1][e]);        \
    const float rowm = fmaxf(pmax, __shfl_xor(pmax, 32));                               \
    if (__any(rowm > mrow + 5.5451774f)) {      /* T13 defer-max, THR = 8*ln2 */        \
      const float mnew  = fmaxf(mrow, rowm);                                            \
      const float alpha = __expf(mrow - mnew);                                          \
      lsum *= alpha;                                                                    \
      _Pragma("unroll") for (int d0 = 0; d0 < 2; d0++)                                  \
        _Pragma("unroll") for (int e = 0; e < 16; e++) o[d0][e] *= alpha;               \
      mrow = mnew;                                                                      \
    }                                                                                   \
    _Pragma("unroll") for (int tt = 0; tt < 2; tt++)                                    \
      _Pragma("unroll") for (int e = 0; e < 16; e++) st[tt][e] = __expf(st[tt][e] - mrow); \
    float psum = 0.f;                                                                   \
    _Pragma("unroll") for (int tt = 0; tt < 2; tt++)                                    \
      _Pragma("unroll") for (int e = 0; e < 16; e++) psum += st[tt][e];                 \
    lsum += psum + __shfl_xor(psum, 32);                                                \
    short8 pb[4];                                                                       \
    _Pragma("unroll")                                                                   \
    for (int tt = 0; tt < 2; tt++) {                                                    \
      _Pragma("unroll")                                                                 \
      for (int g = 0; g < 2; g++) {                                                     \
        /* own words: w0 kv=16g+{0,1}+4hi, w1 kv=16g+{2,3}+4hi,                         \
                      w2 kv=16g+8+{0,1}+4hi, w3 kv=16g+8+{2,3}+4hi                      \
           B-frag element (hi,i) needs kv = 16g + 8*hi + i                           */ \
        u32 w0 = cvtpk(st[tt][8*g + 0], st[tt][8*g + 1]);                               \
        u32 w1 = cvtpk(st[tt][8*g + 2], st[tt][8*g + 3]);                               \
        u32 w2 = cvtpk(st[tt][8*g + 4], st[tt][8*g + 5]);                               \
        u32 w3 = cvtpk(st[tt][8*g + 6], st[tt][8*g + 7]);                               \
        u32 w0x = (u32)__shfl_xor((int)w0, 32);                                         \
        u32 w1x = (u32)__shfl_xor((int)w1, 32);                                         \
        u32 w2x = (u32)__shfl_xor((int)w2, 32);                                         \
        u32 w3x = (u32)__shfl_xor((int)w3, 32);                                         \
        union { u32 wd[4]; short8 s8; } uu;                                             \
        uu.wd[0] = hi ? w2x : w0;                                                       \
        uu.wd[1] = hi ? w3x : w1;                                                       \
        uu.wd[2] = hi ? w2  : w0x;                                                      \
        uu.wd[3] = hi ? w3  : w1x;                                                      \
        pb[2*tt + g] = uu.s8;                                                           \
      }                                                                                 \
    }                                                                                   \
    _Pragma("unroll")                                                                   \
    for (int ks = 0; ks < 4; ks++) {                                                    \
      short8 vf0 = *(const short8*)&v_lds[(CUR) + (l31)*64      + ((ks*16 + hi*8) ^ swzl)]; \
      short8 vf1 = *(const short8*)&v_lds[(CUR) + (32 + l31)*64 + ((ks*16 + hi*8) ^ swzl)]; \
      o[0] = __builtin_amdgcn_mfma_f32_32x32x16_bf16(vf0, pb[ks], o[0], 0, 0, 0);       \
      o[1] = __builtin_amdgcn_mfma_f32_32x32x16_bf16(vf1, pb[ks], o[1], 0, 0, 0);       \
    }                                                                                   \
    *(short8*)&k_lds[(NXT) + kd0] = kr0; *(short8*)&k_lds[(NXT) + kd1] = kr1;           \
    *(short8*)&v_lds[(NXT) + kd0] = vr0; *(short8*)&v_lds[(NXT) + kd1] = vr1;           \
  }

    for (int it = 0; it < 8; it++) {
        DO_TILE(0, 8192)                 // compute t,   write t+2 -> buf2
        DO_TILE(4096, 12288)             // compute t+1, write t+3 -> buf3
        __syncthreads();                 // buf2/3 ready; buf0/1 reads done
        DO_TILE(8192, 0)                 // compute t+2, write t+4 -> buf0
        DO_TILE(12288, 4096)             // compute t+3, write t+5 -> buf1
        __syncthreads();                 // buf0/1 ready; buf2/3 reads done
    }
#undef DO_TILE

    // epilogue: O^T layout col=q (lane-local), row d = d0*32 + 8s + 4hi + j
    const float invl = 1.0f / lsum;
    u16* op = out + (size_t)(bb * 2048 + q0 + l31) * 1024 + h * 64;
    #pragma unroll
    for (int d0 = 0; d0 < 2; d0++) {
        #pragma unroll
        for (int s = 0; s < 4; s++) {
            u32x2 pr;
            pr.x = cvtpk(o[d0][4*s + 0] * invl, o[d0][4*s + 1] * invl);
            pr.y = cvtpk(o[d0][4*s + 2] * invl, o[d0][4*s + 3] * invl);
            *(u32x2*)(op + d0 * 32 + s * 8 + hi * 4) = pr;
        }
    }
}

// ---------- launcher ----------
extern "C" void kernel_launch(void* const* d_in, const int* in_sizes, int n_in,
                              void* d_out, int out_size, void* d_ws, size_t ws_size,
                              hipStream_t stream) {
    const float* x     = (const float*)d_in[0];   // [2,2048,1024]
    const float* w_qkv = (const float*)d_in[1];   // [1024,3072]
    const float* w_out = (const float*)d_in[2];   // [1024,1024]
    const float* b_out = (const float*)d_in[3];   // [1024]

    char* ws = (char*)d_ws;
    u16* xb    = (u16*)(ws);                          //  8 MB  x bf16 [4096,1024]
    u16* wqkvT = (u16*)(ws + (size_t)( 8u << 20));    //  6 MB  w_qkv^T bf16 [3072,1024]
    u16* woutT = (u16*)(ws + (size_t)(14u << 20));    //  2 MB  w_out^T bf16 [1024,1024]
    u16* qkvb  = (u16*)(ws + (size_t)(16u << 20));    // 24 MB  q,k bf16 [4096,3072]
    u16* vtb   = (u16*)(ws + (size_t)(40u << 20));    //  8 MB  v^T bf16 [b,h,64,2048]
    u16* aout  = (u16*)(ws + (size_t)(48u << 20));    //  8 MB  attn out bf16 [4096,1024]

    prep_fused<<<3072, 256, 0, stream>>>(x, w_qkv, w_out, xb, wqkvT, woutT);

    gemm128<<<dim3(24, 32), 256, 0, stream>>>(xb, wqkvT, qkvb, vtb, 4096, 3072, 1024);
    attn_kernel<<<dim3(16, 16, 2), 256, 0, stream>>>(qkvb, vtb, aout);

    gemm64n<<<dim3(8, 64), 256, 0, stream>>>(aout, woutT, (float*)d_out, b_out,
                                             4096, 1024, 1024);
}

// Round 26
// 118.069 us; speedup vs baseline: 1.0186x; 1.0010x over previous
//
#include <hip/hip_runtime.h>
#include <hip/hip_bf16.h>

typedef unsigned short u16;
typedef unsigned int u32;
typedef __attribute__((ext_vector_type(8))) short short8;
typedef __attribute__((ext_vector_type(4))) float f32x4;
typedef __attribute__((ext_vector_type(16))) float f32x16;
typedef __attribute__((ext_vector_type(2))) u32 u32x2;

typedef __attribute__((address_space(1))) void as1_void;
typedef __attribute__((address_space(3))) void as3_void;

// ---------- helpers ----------
__device__ __forceinline__ u16 f2b(float x) {
    union { float f; u32 u; } c; c.f = x;
    u32 r = c.u + 0x7fffu + ((c.u >> 16) & 1u);   // RNE, finite inputs
    return (u16)(r >> 16);
}
__device__ __forceinline__ float b2f(u16 x) {
    union { u32 u; float f; } c; c.u = ((u32)x) << 16;
    return c.f;
}
__device__ __forceinline__ u32 cvtpk(float lo, float hi) {   // S0 -> low16
    u32 r;
    asm("v_cvt_pk_bf16_f32 %0, %1, %2" : "=v"(r) : "v"(lo), "v"(hi));
    return r;
}
// async global->LDS, 16B per lane; LDS dest = wave-uniform base + lane*16
__device__ __forceinline__ void gload16(const u16* g, u16* l) {
    __builtin_amdgcn_global_load_lds((as1_void*)(u16*)g, (as3_void*)l, 16, 0, 0);
}
__device__ __forceinline__ void barrier_raw() {
    asm volatile("" ::: "memory");
    __builtin_amdgcn_s_barrier();
    asm volatile("" ::: "memory");
}

// ---------- fused prep: x fp32->bf16 convert + both weight transposes ----------
__device__ __forceinline__ void tbody(const float* __restrict__ in, u16* __restrict__ out,
                                      int R, int C, int r0, int c0, int t,
                                      u16 (&tile)[64][72]) {
    {
        const int rr = t >> 2;
        const int cq = (t & 3) * 16;
        const float* src = in + (size_t)(r0 + rr) * C + c0 + cq;
        #pragma unroll
        for (int j = 0; j < 4; j++) {
            float4 v = *(const float4*)(src + j * 4);
            tile[cq + j*4 + 0][rr] = f2b(v.x);
            tile[cq + j*4 + 1][rr] = f2b(v.y);
            tile[cq + j*4 + 2][rr] = f2b(v.z);
            tile[cq + j*4 + 3][rr] = f2b(v.w);
        }
    }
    __syncthreads();
    {
        const int cc = t >> 2;
        const int rq = (t & 3) * 16;
        u16* dst = out + (size_t)(c0 + cc) * R + r0 + rq;
        *(short8*)(dst)     = *(const short8*)&tile[cc][rq];
        *(short8*)(dst + 8) = *(const short8*)&tile[cc][rq + 8];
    }
}

__global__ __launch_bounds__(256) void prep_fused(const float* __restrict__ x,
                                                  const float* __restrict__ w_qkv,
                                                  const float* __restrict__ w_out,
                                                  u16* __restrict__ xb,
                                                  u16* __restrict__ wqkvT,
                                                  u16* __restrict__ woutT) {
    __shared__ u16 tile[64][72];
    const int b = blockIdx.x, t = threadIdx.x;
    if (b < 2048) {                       // x convert: 2048 blocks x 256 thr x 8 elems
        const int i = b * 256 + t;
        const float4* p = (const float4*)(x + (size_t)i * 8);
        float4 a = p[0], c = p[1];
        short8 v;
        v[0]=(short)f2b(a.x); v[1]=(short)f2b(a.y); v[2]=(short)f2b(a.z); v[3]=(short)f2b(a.w);
        v[4]=(short)f2b(c.x); v[5]=(short)f2b(c.y); v[6]=(short)f2b(c.z); v[7]=(short)f2b(c.w);
        *(short8*)(xb + (size_t)i * 8) = v;
    } else if (b < 2816) {                // w_qkv^T: 768 blocks == old dim3(48,16)
        const int bb = b - 2048;
        tbody(w_qkv, wqkvT, 1024, 3072, (bb / 48) * 64, (bb % 48) * 64, t, tile);
    } else {                              // w_out^T: 256 blocks == old dim3(16,16)
        const int bb = b - 2816;
        tbody(w_out, woutT, 1024, 1024, (bb >> 4) * 64, (bb & 15) * 64, t, tile);
    }
}

// ---------- bf16 GEMM (QKV): counted-vmcnt double-buffered global_load_lds ----
// 128x128 tile, BK=32, 4 waves (2x2), 16x16x32 MFMA. XCD-aware block swizzle.
// LDS bank swizzle: slot ^= (row>>1)&3 on BOTH the pre-swizzled global source
// and the ds_read address (involution).
// u16 out; V columns (>=2048) stored transposed into vt[b,h,d,n].
__global__ __launch_bounds__(256) void gemm128(const u16* __restrict__ A,
                                               const u16* __restrict__ Bt,
                                               u16* __restrict__ Cp,
                                               u16* __restrict__ vt,
                                               int M, int Nn, int K) {
    __shared__ __align__(16) u16 a_lds[2][128 * 32];
    __shared__ __align__(16) u16 b_lds[2][128 * 32];
    const int tid = threadIdx.x;
    const int w = tid >> 6, l = tid & 63;
    const int l16 = l & 15, lg = l >> 4;
    const int nbx = gridDim.x;
    const int flat = blockIdx.x + nbx * blockIdx.y;
    const int cpx = (nbx * gridDim.y) >> 3;
    const int logical = (flat & 7) * cpx + (flat >> 3);
    const int m0 = (logical / nbx) * 128, n0 = (logical % nbx) * 128;
    const int wm = w >> 1, wn = w & 1;
    const int lr = l >> 2;               // lane row-in-call 0..15
    const int scol = (((l & 3) ^ ((lr >> 1) & 3)) * 8);   // u16 col, pre-swizzled
    const int rsl = (lg ^ ((l16 >> 1) & 3)) * 8;          // read-side swizzled slot

    f32x4 acc[4][4];
    #pragma unroll
    for (int i = 0; i < 4; i++)
        #pragma unroll
        for (int j = 0; j < 4; j++) { f32x4 z = {0.f,0.f,0.f,0.f}; acc[i][j] = z; }

    const u16* Ap = A  + (size_t)m0 * K;
    const u16* Bp = Bt + (size_t)n0 * K;

#define STAGE(BUF, KOF)                                                              \
    _Pragma("unroll")                                                                \
    for (int j = 0; j < 2; j++) {                                                    \
        const int r = w * 32 + j * 16;                                               \
        gload16(Ap + (size_t)(r + lr) * K + (KOF) + scol, &a_lds[(BUF)][r * 32]);    \
        gload16(Bp + (size_t)(r + lr) * K + (KOF) + scol, &b_lds[(BUF)][r * 32]);    \
    }

    const int nk = K >> 5;
    STAGE(0, 0)
    int cur = 0;
    for (int kt = 0; kt < nk; kt++) {
        if (kt + 1 < nk) {               // prefetch next tile; 4 loads stay in flight
            STAGE(cur ^ 1, (kt + 1) << 5)
            __builtin_amdgcn_sched_barrier(0);   // pin loads above the wait
            asm volatile("s_waitcnt vmcnt(4)" ::: "memory");
            __builtin_amdgcn_sched_barrier(0);
        } else {
            __builtin_amdgcn_sched_barrier(0);
            asm volatile("s_waitcnt vmcnt(0)" ::: "memory");
            __builtin_amdgcn_sched_barrier(0);
        }
        barrier_raw();                   // everyone's current tile landed
        short8 af[4], bf8[4];
        #pragma unroll
        for (int mb = 0; mb < 4; mb++)
            af[mb] = *(const short8*)&a_lds[cur][(wm * 64 + mb * 16 + l16) * 32 + rsl];
        #pragma unroll
        for (int nb = 0; nb < 4; nb++)
            bf8[nb] = *(const short8*)&b_lds[cur][(wn * 64 + nb * 16 + l16) * 32 + rsl];
        #pragma unroll
        for (int mb = 0; mb < 4; mb++)
            #pragma unroll
            for (int nb = 0; nb < 4; nb++)
                acc[mb][nb] = __builtin_amdgcn_mfma_f32_16x16x32_bf16(af[mb], bf8[nb], acc[mb][nb], 0, 0, 0);
        barrier_raw();                   // reads done before next overwrite
        cur ^= 1;
    }
#undef STAGE

    #pragma unroll
    for (int mb = 0; mb < 4; mb++) {
        #pragma unroll
        for (int nb = 0; nb < 4; nb++) {
            const int col = n0 + wn * 64 + nb * 16 + l16;
            const int row0 = m0 + wm * 64 + mb * 16 + lg * 4;
            if (col < 2048) {            // Q,K: row-major
                #pragma unroll
                for (int r = 0; r < 4; r++)
                    Cp[(size_t)(row0 + r) * Nn + col] = f2b(acc[mb][nb][r]);
            } else {                     // V: transposed into vt[b,h,d,n], 8B packed
                const int hd = col - 2048;
                const int hh = hd >> 6, d = hd & 63;
                const int bi = row0 >> 11, n = row0 & 2047;
                u32x2 pr;
                pr.x = cvtpk(acc[mb][nb][0], acc[mb][nb][1]);
                pr.y = cvtpk(acc[mb][nb][2], acc[mb][nb][3]);
                *(u32x2*)(vt + ((size_t)((bi * 16 + hh) * 64 + d)) * 2048 + n) = pr;
            }
        }
    }
}

// ---------- bf16 GEMM (out-proj): 64x128 tile, fp32+bias epilogue ----------
// Same structure as gemm128 re-parameterized: 4 waves 2x2 over 64x128 (per-wave
// 32x64, acc[2][4]); A-tile 64 rows (1 gload16/wave), vmcnt(3) (3 loads/stage).
// Grid (8,64) = 512 blocks -> 2 blocks/CU so barrier stalls overlap.
__global__ __launch_bounds__(256) void gemm64n(const u16* __restrict__ A,
                                               const u16* __restrict__ Bt,
                                               float* __restrict__ Cp,
                                               const float* __restrict__ bias,
                                               int M, int Nn, int K) {
    __shared__ __align__(16) u16 a_lds[2][64 * 32];
    __shared__ __align__(16) u16 b_lds[2][128 * 32];
    const int tid = threadIdx.x;
    const int w = tid >> 6, l = tid & 63;
    const int l16 = l & 15, lg = l >> 4;
    const int nbx = gridDim.x;
    const int flat = blockIdx.x + nbx * blockIdx.y;
    const int cpx = (nbx * gridDim.y) >> 3;
    const int logical = (flat & 7) * cpx + (flat >> 3);
    const int m0 = (logical / nbx) * 64, n0 = (logical % nbx) * 128;
    const int wm = w >> 1, wn = w & 1;
    const int lr = l >> 2;               // lane row-in-call 0..15
    const int scol = (((l & 3) ^ ((lr >> 1) & 3)) * 8);   // u16 col, pre-swizzled
    const int rsl = (lg ^ ((l16 >> 1) & 3)) * 8;          // read-side swizzled slot

    f32x4 acc[2][4];
    #pragma unroll
    for (int i = 0; i < 2; i++)
        #pragma unroll
        for (int j = 0; j < 4; j++) { f32x4 z = {0.f,0.f,0.f,0.f}; acc[i][j] = z; }

    const u16* Ap = A  + (size_t)m0 * K;
    const u16* Bp = Bt + (size_t)n0 * K;

#define STAGE64(BUF, KOF)                                                            \
    gload16(Ap + (size_t)(w * 16 + lr) * K + (KOF) + scol, &a_lds[(BUF)][w * 16 * 32]); \
    _Pragma("unroll")                                                                \
    for (int j = 0; j < 2; j++) {                                                    \
        const int r = w * 32 + j * 16;                                               \
        gload16(Bp + (size_t)(r + lr) * K + (KOF) + scol, &b_lds[(BUF)][r * 32]);    \
    }

    const int nk = K >> 5;
    STAGE64(0, 0)
    int cur = 0;
    for (int kt = 0; kt < nk; kt++) {
        if (kt + 1 < nk) {               // prefetch next tile; 3 loads stay in flight
            STAGE64(cur ^ 1, (kt + 1) << 5)
            __builtin_amdgcn_sched_barrier(0);
            asm volatile("s_waitcnt vmcnt(3)" ::: "memory");
            __builtin_amdgcn_sched_barrier(0);
        } else {
            __builtin_amdgcn_sched_barrier(0);
            asm volatile("s_waitcnt vmcnt(0)" ::: "memory");
            __builtin_amdgcn_sched_barrier(0);
        }
        barrier_raw();                   // everyone's current tile landed
        short8 af[2], bf8[4];
        #pragma unroll
        for (int mb = 0; mb < 2; mb++)
            af[mb] = *(const short8*)&a_lds[cur][(wm * 32 + mb * 16 + l16) * 32 + rsl];
        #pragma unroll
        for (int nb = 0; nb < 4; nb++)
            bf8[nb] = *(const short8*)&b_lds[cur][(wn * 64 + nb * 16 + l16) * 32 + rsl];
        #pragma unroll
        for (int mb = 0; mb < 2; mb++)
            #pragma unroll
            for (int nb = 0; nb < 4; nb++)
                acc[mb][nb] = __builtin_amdgcn_mfma_f32_16x16x32_bf16(af[mb], bf8[nb], acc[mb][nb], 0, 0, 0);
        barrier_raw();                   // reads done before next overwrite
        cur ^= 1;
    }
#undef STAGE64

    #pragma unroll
    for (int mb = 0; mb < 2; mb++) {
        #pragma unroll
        for (int nb = 0; nb < 4; nb++) {
            const int col = n0 + wn * 64 + nb * 16 + l16;
            const int row0 = m0 + wm * 32 + mb * 16 + lg * 4;
            #pragma unroll
            for (int r = 0; r < 4; r++)
                Cp[(size_t)(row0 + r) * Nn + col] = acc[mb][nb][r] + bias[col];
        }
    }
}

// ---------- flash attention: 4 waves x 32 Q-rows, swapped QK^T / PV ----------
// Final: 4-buffer rotation, 2 KV-tiles per barrier period (16 barriers),
// serial row reductions, reg-staged K/V.
__global__ __launch_bounds__(256, 2) void attn_kernel(const u16* __restrict__ qkv,
                                                      const u16* __restrict__ vt,
                                                      u16* __restrict__ out) {
    __shared__ __align__(16) u16 k_lds[16384];  // 4 bufs x [64 kv][64 d] swizzled
    __shared__ __align__(16) u16 v_lds[16384];  // 4 bufs x [64 d][64 kv] swizzled
    const int tid = threadIdx.x;
    const int w = tid >> 6, l = tid & 63;
    const int l31 = l & 31, hi = l >> 5;
    // XCD swizzle: 512 blocks, cpx=64 -> each XCD owns 4 full (b,h) KV groups
    const int flat = blockIdx.x + (blockIdx.y << 4) + (blockIdx.z << 8);
    const int logical = (flat & 7) * 64 + (flat >> 3);
    const int xq = logical & 15, h = (logical >> 4) & 15, bb = logical >> 8;
    const int q0 = xq * 128 + w * 32;
    const int swzl = (l31 & 7) << 3;            // u16-unit XOR for 16B-slot swizzle

    // Q fragments, pre-scaled by 0.125 (exact exponent shift in bf16)
    const u16* qp = qkv + (size_t)(bb * 2048 + q0 + l31) * 3072 + h * 64 + hi * 8;
    short8 qf[4];
    #pragma unroll
    for (int c4 = 0; c4 < 4; c4++) {
        short8 v = *(const short8*)(qp + c4 * 16);
        #pragma unroll
        for (int e = 0; e < 8; e++) v[e] = (short)f2b(b2f((u16)v[e]) * 0.125f);
        qf[c4] = v;
    }

    f32x16 o[2];
    #pragma unroll
    for (int d0 = 0; d0 < 2; d0++)
        #pragma unroll
        for (int e = 0; e < 16; e++) o[d0][e] = 0.f;
    float mrow = -1e30f, lsum = 0.f;

    // staging: 256 threads, 2 slots/thread per matrix; row = tid>>2, slots {sc, sc+4}
    const int srow = tid >> 2, sc = tid & 3;
    const int kd0 = srow * 64 + ((sc ^ (srow & 7)) * 8);
    const int kd1 = srow * 64 + (((sc + 4) ^ (srow & 7)) * 8);
    const u16* ksrc = qkv + (size_t)(bb * 2048 + srow) * 3072 + 1024 + h * 64 + sc * 8;
    const u16* vsrc = vt + (size_t)((bb * 16 + h) * 64 + srow) * 2048 + sc * 8;

    short8 kr0, kr1, vr0, vr1;
    // prologue: fill bufs 0 (tile 0) and 4096 (tile 1)
    kr0 = *(const short8*)ksrc; kr1 = *(const short8*)(ksrc + 32);
    vr0 = *(const short8*)vsrc; vr1 = *(const short8*)(vsrc + 32);
    ksrc += 64 * 3072; vsrc += 64;
    *(short8*)&k_lds[kd0] = kr0; *(short8*)&k_lds[kd1] = kr1;
    *(short8*)&v_lds[kd0] = vr0; *(short8*)&v_lds[kd1] = vr1;
    kr0 = *(const short8*)ksrc; kr1 = *(const short8*)(ksrc + 32);
    vr0 = *(const short8*)vsrc; vr1 = *(const short8*)(vsrc + 32);
    ksrc += 64 * 3072; vsrc += 64;
    *(short8*)&k_lds[4096 + kd0] = kr0; *(short8*)&k_lds[4096 + kd1] = kr1;
    *(short8*)&v_lds[4096 + kd0] = vr0; *(short8*)&v_lds[4096 + kd1] = vr1;
    __syncthreads();

// DO_TILE: load regs for tile L (ksrc cursor), compute CUR, write L into NXT.
// No trailing barrier — barriers are placed per half-period in the loop.
#define DO_TILE(CUR, NXT)                                                               \
  {                                                                                     \
    kr0 = *(const short8*)ksrc; kr1 = *(const short8*)(ksrc + 32);                      \
    vr0 = *(const short8*)vsrc; vr1 = *(const short8*)(vsrc + 32);                      \
    ksrc += 64 * 3072; vsrc += 64;                                                      \
    f32x16 st[2];                                                                       \
    _Pragma("unroll") for (int tt = 0; tt < 2; tt++)                                    \
      _Pragma("unroll") for (int e = 0; e < 16; e++) st[tt][e] = 0.f;                   \
    _Pragma("unroll")                                                                   \
    for (int c4 = 0; c4 < 4; c4++) {                                                    \
      short8 kf0 = *(const short8*)&k_lds[(CUR) + (l31)*64      + ((c4*16 + hi*8) ^ swzl)]; \
      short8 kf1 = *(const short8*)&k_lds[(CUR) + (32 + l31)*64 + ((c4*16 + hi*8) ^ swzl)]; \
      st[0] = __builtin_amdgcn_mfma_f32_32x32x16_bf16(kf0, qf[c4], st[0], 0, 0, 0);     \
      st[1] = __builtin_amdgcn_mfma_f32_32x32x16_bf16(kf1, qf[c4], st[1], 0, 0, 0);     \
    }                                                                                   \
    float pmax = st[0][0];                                                              \
    _Pragma("unroll") for (int e = 1; e < 16; e++) pmax = fmaxf(pmax, st[0][e]);        \
    _Pragma("unroll") for (int e = 0; e < 16; e++) pmax = fmaxf(pmax, st[1][e]);        \
    const float rowm = fmaxf(pmax, __shfl_xor(pmax, 32));                               \
    if (__any(rowm > mrow + 5.5451774f)) {      /* T13 defer-max, THR = 8*ln2 */        \
      const float mnew  = fmaxf(mrow, rowm);                                            \
      const float alpha = __expf(mrow - mnew);                                          \
      lsum *= alpha;                                                                    \
      _Pragma("unroll") for (int d0 = 0; d0 < 2; d0++)                                  \
        _Pragma("unroll") for (int e = 0; e < 16; e++) o[d0][e] *= alpha;               \
      mrow = mnew;                                                                      \
    }                                                                                   \
    _Pragma("unroll") for (int tt = 0; tt < 2; tt++)                                    \
      _Pragma("unroll") for (int e = 0; e < 16; e++) st[tt][e] = __expf(st[tt][e] - mrow); \
    float psum = 0.f;                                                                   \
    _Pragma("unroll") for (int tt = 0; tt < 2; tt++)                                    \
      _Pragma("unroll") for (int e = 0; e < 16; e++) psum += st[tt][e];                 \
    lsum += psum + __shfl_xor(psum, 32);                                                \
    short8 pb[4];                                                                       \
    _Pragma("unroll")                                                                   \
    for (int tt = 0; tt < 2; tt++) {                                                    \
      _Pragma("unroll")                                                                 \
      for (int g = 0; g < 2; g++) {                                                     \
        /* own words: w0 kv=16g+{0,1}+4hi, w1 kv=16g+{2,3}+4hi,                         \
                      w2 kv=16g+8+{0,1}+4hi, w3 kv=16g+8+{2,3}+4hi                      \
           B-frag element (hi,i) needs kv = 16g + 8*hi + i                           */ \
        u32 w0 = cvtpk(st[tt][8*g + 0], st[tt][8*g + 1]);                               \
        u32 w1 = cvtpk(st[tt][8*g + 2], st[tt][8*g + 3]);                               \
        u32 w2 = cvtpk(st[tt][8*g + 4], st[tt][8*g + 5]);                               \
        u32 w3 = cvtpk(st[tt][8*g + 6], st[tt][8*g + 7]);                               \
        u32 w0x = (u32)__shfl_xor((int)w0, 32);                                         \
        u32 w1x = (u32)__shfl_xor((int)w1, 32);                                         \
        u32 w2x = (u32)__shfl_xor((int)w2, 32);                                         \
        u32 w3x = (u32)__shfl_xor((int)w3, 32);                                         \
        union { u32 wd[4]; short8 s8; } uu;                                             \
        uu.wd[0] = hi ? w2x : w0;                                                       \
        uu.wd[1] = hi ? w3x : w1;                                                       \
        uu.wd[2] = hi ? w2  : w0x;                                                      \
        uu.wd[3] = hi ? w3  : w1x;                                                      \
        pb[2*tt + g] = uu.s8;                                                           \
      }                                                                                 \
    }                                                                                   \
    _Pragma("unroll")                                                                   \
    for (int ks = 0; ks < 4; ks++) {                                                    \
      short8 vf0 = *(const short8*)&v_lds[(CUR) + (l31)*64      + ((ks*16 + hi*8) ^ swzl)]; \
      short8 vf1 = *(const short8*)&v_lds[(CUR) + (32 + l31)*64 + ((ks*16 + hi*8) ^ swzl)]; \
      o[0] = __builtin_amdgcn_mfma_f32_32x32x16_bf16(vf0, pb[ks], o[0], 0, 0, 0);       \
      o[1] = __builtin_amdgcn_mfma_f32_32x32x16_bf16(vf1, pb[ks], o[1], 0, 0, 0);       \
    }                                                                                   \
    *(short8*)&k_lds[(NXT) + kd0] = kr0; *(short8*)&k_lds[(NXT) + kd1] = kr1;           \
    *(short8*)&v_lds[(NXT) + kd0] = vr0; *(short8*)&v_lds[(NXT) + kd1] = vr1;           \
  }

    for (int it = 0; it < 8; it++) {
        DO_TILE(0, 8192)                 // compute t,   write t+2 -> buf2
        DO_TILE(4096, 12288)             // compute t+1, write t+3 -> buf3
        __syncthreads();                 // buf2/3 ready; buf0/1 reads done
        DO_TILE(8192, 0)                 // compute t+2, write t+4 -> buf0
        DO_TILE(12288, 4096)             // compute t+3, write t+5 -> buf1
        __syncthreads();                 // buf0/1 ready; buf2/3 reads done
    }
#undef DO_TILE

    // epilogue: O^T layout col=q (lane-local), row d = d0*32 + 8s + 4hi + j
    const float invl = 1.0f / lsum;
    u16* op = out + (size_t)(bb * 2048 + q0 + l31) * 1024 + h * 64;
    #pragma unroll
    for (int d0 = 0; d0 < 2; d0++) {
        #pragma unroll
        for (int s = 0; s < 4; s++) {
            u32x2 pr;
            pr.x = cvtpk(o[d0][4*s + 0] * invl, o[d0][4*s + 1] * invl);
            pr.y = cvtpk(o[d0][4*s + 2] * invl, o[d0][4*s + 3] * invl);
            *(u32x2*)(op + d0 * 32 + s * 8 + hi * 4) = pr;
        }
    }
}

// ---------- launcher ----------
extern "C" void kernel_launch(void* const* d_in, const int* in_sizes, int n_in,
                              void* d_out, int out_size, void* d_ws, size_t ws_size,
                              hipStream_t stream) {
    const float* x     = (const float*)d_in[0];   // [2,2048,1024]
    const float* w_qkv = (const float*)d_in[1];   // [1024,3072]
    const float* w_out = (const float*)d_in[2];   // [1024,1024]
    const float* b_out = (const float*)d_in[3];   // [1024]

    char* ws = (char*)d_ws;
    u16* xb    = (u16*)(ws);                          //  8 MB  x bf16 [4096,1024]
    u16* wqkvT = (u16*)(ws + (size_t)( 8u << 20));    //  6 MB  w_qkv^T bf16 [3072,1024]
    u16* woutT = (u16*)(ws + (size_t)(14u << 20));    //  2 MB  w_out^T bf16 [1024,1024]
    u16* qkvb  = (u16*)(ws + (size_t)(16u << 20));    // 24 MB  q,k bf16 [4096,3072]
    u16* vtb   = (u16*)(ws + (size_t)(40u << 20));    //  8 MB  v^T bf16 [b,h,64,2048]
    u16* aout  = (u16*)(ws + (size_t)(48u << 20));    //  8 MB  attn out bf16 [4096,1024]

    prep_fused<<<3072, 256, 0, stream>>>(x, w_qkv, w_out, xb, wqkvT, woutT);

    gemm128<<<dim3(24, 32), 256, 0, stream>>>(xb, wqkvT, qkvb, vtb, 4096, 3072, 1024);
    attn_kernel<<<dim3(16, 16, 2), 256, 0, stream>>>(qkvb, vtb, aout);

    gemm64n<<<dim3(8, 64), 256, 0, stream>>>(aout, woutT, (float*)d_out, b_out,
                                             4096, 1024, 1024);
}